// Round 1
// baseline (430.221 us; speedup 1.0000x reference)
//
#include <hip/hip_runtime.h>

#define TSIZE 151
#define HSLOTS 152          // bins 0..151 (k+1 can reach 151 only after clamp)
#define SUPPORT 512
#define TARGET 65024
#define NCLS 64

// Workspace layout (zeroed every launch via hipMemsetAsync)
struct Accum {
    float hist_all[HSLOTS];          // soft histogram of ALL elements
    float hist_pos[HSLOTS];          // soft histogram of positive-mask elements
    float nll_sum;                   // sum of per-row NLL
    float pad0;
    int   sup_cnt[NCLS];             // support label counts per class
    int   tgt_cnt[NCLS];             // target label counts per class
    unsigned long long mask[NCLS * 8]; // per-class 512-bit support membership mask
};

// ---------------------------------------------------------------- prep
__global__ void prep_kernel(const int* __restrict__ labels, Accum* ws) {
    int j = threadIdx.x;
    if (j < SUPPORT) {
        int c = labels[j];
        atomicOr(&ws->mask[c * 8 + (j >> 6)], 1ull << (j & 63));
        atomicAdd(&ws->sup_cnt[c], 1);
    }
}

// ---------------------------------------------------------------- histogram
// One block iteration = one target row (512 cols): 256 threads x float2.
__global__ __launch_bounds__(256) void hist_kernel(const float* __restrict__ ip,
                                                   const int* __restrict__ labels,
                                                   Accum* __restrict__ ws) {
    __shared__ float h_all[4][HSLOTS];
    __shared__ float h_pos[4][HSLOTS];
    const int tid  = threadIdx.x;
    const int wid  = tid >> 6;
    const int lane = tid & 63;
    for (int s = lane; s < HSLOTS; s += 64) {
        h_all[wid][s] = 0.0f;
        h_pos[wid][s] = 0.0f;
    }
    __syncthreads();

    const int mword = tid >> 5;          // which u64 of the 512-bit mask (j/64 for j=2*tid)
    const int b0    = (tid << 1) & 63;   // bit of column j=2*tid

    for (int row = blockIdx.x; row < TARGET; row += gridDim.x) {
        const int lab = labels[SUPPORT + row];
        const unsigned long long mw = ws->mask[lab * 8 + mword];
        const float2 v = reinterpret_cast<const float2*>(ip + (size_t)row * SUPPORT)[tid];

        {   // column j = 2*tid
            float u  = v.x * 75.0f;          // s / (2/150)
            float kf = floorf(u);
            float fr = u - kf;
            int k = (int)kf + 75;
            k = k < 0 ? 0 : (k > 150 ? 150 : k);
            atomicAdd(&h_all[wid][k],     fr);
            atomicAdd(&h_all[wid][k + 1], 1.0f - fr);
            if ((mw >> b0) & 1ull) {
                atomicAdd(&h_pos[wid][k],     fr);
                atomicAdd(&h_pos[wid][k + 1], 1.0f - fr);
            }
        }
        {   // column j = 2*tid + 1
            float u  = v.y * 75.0f;
            float kf = floorf(u);
            float fr = u - kf;
            int k = (int)kf + 75;
            k = k < 0 ? 0 : (k > 150 ? 150 : k);
            atomicAdd(&h_all[wid][k],     fr);
            atomicAdd(&h_all[wid][k + 1], 1.0f - fr);
            if ((mw >> (b0 + 1)) & 1ull) {
                atomicAdd(&h_pos[wid][k],     fr);
                atomicAdd(&h_pos[wid][k + 1], 1.0f - fr);
            }
        }
    }

    __syncthreads();
    for (int idx = tid; idx < 2 * HSLOTS; idx += 256) {
        if (idx < HSLOTS) {
            float s = h_all[0][idx] + h_all[1][idx] + h_all[2][idx] + h_all[3][idx];
            if (s != 0.0f) atomicAdd(&ws->hist_all[idx], s);
        } else {
            int i2 = idx - HSLOTS;
            float s = h_pos[0][i2] + h_pos[1][i2] + h_pos[2][i2] + h_pos[3][i2];
            if (s != 0.0f) atomicAdd(&ws->hist_pos[i2], s);
        }
    }
}

// ---------------------------------------------------------------- direct loss
// One wave (64 lanes) per row; lane = class index.
__global__ __launch_bounds__(256) void direct_kernel(const float* __restrict__ logits,
                                                     const int* __restrict__ labels,
                                                     Accum* __restrict__ ws) {
    __shared__ int ltc[NCLS];
    if (threadIdx.x < NCLS) ltc[threadIdx.x] = 0;
    __syncthreads();

    const int wid  = threadIdx.x >> 6;
    const int lane = threadIdx.x & 63;
    const int wglb = blockIdx.x * 4 + wid;
    const int nw   = gridDim.x * 4;

    float lsum = 0.0f;
    for (int row = wglb; row < TARGET; row += nw) {
        const int lab = labels[SUPPORT + row];
        const float x = logits[(size_t)row * NCLS + lane];
        float m = x;
        for (int off = 32; off; off >>= 1) m = fmaxf(m, __shfl_xor(m, off));
        float e = __expf(x - m);
        float ssum = e;
        for (int off = 32; off; off >>= 1) ssum += __shfl_xor(ssum, off);
        float xl = __shfl(x, lab);
        if (lane == 0) {
            lsum += m + __logf(ssum) - xl;
            atomicAdd(&ltc[lab], 1);
        }
    }
    if (lane == 0 && lsum != 0.0f) atomicAdd(&ws->nll_sum, lsum);
    __syncthreads();
    if (threadIdx.x < NCLS && ltc[threadIdx.x] != 0)
        atomicAdd(&ws->tgt_cnt[threadIdx.x], ltc[threadIdx.x]);
}

// ---------------------------------------------------------------- finalize
__global__ void final_kernel(const Accum* __restrict__ ws, float* __restrict__ out) {
    if (threadIdx.x == 0 && blockIdx.x == 0) {
        long long pos = 0;
        for (int c = 0; c < NCLS; ++c)
            pos += (long long)ws->sup_cnt[c] * (long long)ws->tgt_cnt[c];
        const long long tot = (long long)TARGET * SUPPORT;
        const double posn = (double)pos;
        const double negn = (double)(tot - pos);
        double cdf = 0.0, loss = 0.0;
        for (int t = 0; t < TSIZE; ++t) {
            double hp = (double)ws->hist_pos[t];
            double hn = (double)ws->hist_all[t] - hp;
            cdf  += hp;
            loss += hn * cdf;
        }
        out[0] = (float)(loss / (posn * negn));   // histo_loss
        out[1] = ws->nll_sum / (float)TARGET;     // direct_loss
    }
}

// ---------------------------------------------------------------- launch
extern "C" void kernel_launch(void* const* d_in, const int* in_sizes, int n_in,
                              void* d_out, int out_size, void* d_ws, size_t ws_size,
                              hipStream_t stream) {
    const float* logits = (const float*)d_in[0];   // (65024, 64) f32
    const float* ip     = (const float*)d_in[1];   // (65024, 512) f32
    const int*   labels = (const int*)d_in[2];     // (65536,) int
    float* out = (float*)d_out;
    Accum* ws  = (Accum*)d_ws;

    hipMemsetAsync(ws, 0, sizeof(Accum), stream);
    prep_kernel<<<1, 512, 0, stream>>>(labels, ws);
    hist_kernel<<<2048, 256, 0, stream>>>(ip, labels, ws);
    direct_kernel<<<1024, 256, 0, stream>>>(logits, labels, ws);
    final_kernel<<<1, 64, 0, stream>>>(ws, out);
}

// Round 2
// 397.352 us; speedup vs baseline: 1.0827x; 1.0827x over previous
//
#include <hip/hip_runtime.h>

#define TSIZE   151
#define HB      77            // compact slots: bin k in [75,151] -> slot k-75
#define SUPPORT 512
#define TARGET  65024
#define NCLS    64
#define NPAIR   (TARGET / 2)  // 32512 row-pairs for hist kernel
#define NQUAD   (TARGET / 4)  // 16256 row-quads for direct kernel

struct Accum {
    float hist_all[4][HB];
    float hist_pos[4][HB];
    float nll_sum[8];
    int   sup_cnt[NCLS];
    int   tgt_cnt[NCLS];
    unsigned long long mask[NCLS * 8];   // per-class 512-bit support membership
};

__device__ __forceinline__ void lds_fadd(float* p, float v) {
    __hip_atomic_fetch_add(p, v, __ATOMIC_RELAXED, __HIP_MEMORY_SCOPE_WORKGROUP);
}

// ---------------------------------------------------------------- prep
__global__ void prep_kernel(const int* __restrict__ labels, Accum* ws) {
    int j = threadIdx.x;
    if (j < SUPPORT) {
        int c = labels[j];
        atomicOr(&ws->mask[c * 8 + (j >> 6)], 1ull << (j & 63));
        atomicAdd(&ws->sup_cnt[c], 1);
    }
}

// ---------------------------------------------------------------- histogram
// Block-iteration = one row-pair (1024 floats): 256 threads x float4.
// 32 replicated sub-histograms, copy = lane&31 -> bank == copy (conflict-free).
__global__ __launch_bounds__(256) void hist_kernel(const float* __restrict__ ip,
                                                   const int* __restrict__ labels,
                                                   Accum* __restrict__ ws) {
    __shared__ float hall[HB][32];
    __shared__ float hpos[HB][32];
    const int tid = threadIdx.x;
    const int c   = tid & 31;

    for (int i = tid; i < HB * 32; i += 256) {
        (&hall[0][0])[i] = 0.0f;
        (&hpos[0][0])[i] = 0.0f;
    }
    __syncthreads();

    const int half = tid >> 7;            // which row of the pair
    const int word = (tid & 127) >> 4;    // u64 word of the 512-bit mask
    const int bit0 = (tid << 2) & 63;     // bit of first of the 4 columns

    int rp = blockIdx.x;
    float4 v; int lab = 0; unsigned long long mw = 0;
    if (rp < NPAIR) {
        v   = reinterpret_cast<const float4*>(ip)[rp * 256 + tid];
        lab = labels[SUPPORT + rp * 2 + half];
        mw  = ws->mask[lab * 8 + word];
    }
    while (rp < NPAIR) {
        const int rpn = rp + gridDim.x;
        float4 vn; int labn = 0; unsigned long long mwn = 0;
        if (rpn < NPAIR) {
            vn   = reinterpret_cast<const float4*>(ip)[rpn * 256 + tid];
            labn = labels[SUPPORT + rpn * 2 + half];
            mwn  = ws->mask[labn * 8 + word];
        }
        const unsigned nib = (unsigned)(mw >> bit0) & 0xFu;
        #pragma unroll
        for (int e = 0; e < 4; ++e) {
            const float s  = e == 0 ? v.x : e == 1 ? v.y : e == 2 ? v.z : v.w;
            const float u  = s * 75.0f;           // s / (2/150)
            const float kf = floorf(u);
            const float fr = u - kf;
            int idx = (int)kf;                     // == k - 75
            idx = idx < 0 ? 0 : (idx > 75 ? 75 : idx);
            lds_fadd(&hall[idx][c],     fr);
            lds_fadd(&hall[idx + 1][c], 1.0f - fr);
            if (nib & (1u << e)) {
                lds_fadd(&hpos[idx][c],     fr);
                lds_fadd(&hpos[idx + 1][c], 1.0f - fr);
            }
        }
        v = vn; lab = labn; mw = mwn; rp = rpn;
    }
    __syncthreads();

    // epilogue: one global atomic per (hist,slot), accumulators spread 4x
    if (tid < 2 * HB) {
        const int slot = (tid < HB) ? tid : tid - HB;
        const float* row = (tid < HB) ? hall[slot] : hpos[slot];
        float s = 0.0f;
        const float4* r4 = reinterpret_cast<const float4*>(row);
        #pragma unroll
        for (int i = 0; i < 8; ++i) { float4 q = r4[i]; s += (q.x + q.y) + (q.z + q.w); }
        float* dst = (tid < HB) ? &ws->hist_all[blockIdx.x & 3][slot]
                                : &ws->hist_pos[blockIdx.x & 3][slot];
        if (s != 0.0f) unsafeAtomicAdd(dst, s);
    }
}

// ---------------------------------------------------------------- direct loss
// 4 rows per wave: 16-lane group per row, float4 per lane (16 B).
__global__ __launch_bounds__(256) void direct_kernel(const float* __restrict__ logits,
                                                     const int* __restrict__ labels,
                                                     Accum* __restrict__ ws) {
    __shared__ int   ltc[NCLS];
    __shared__ float wsum[4];
    if (threadIdx.x < NCLS) ltc[threadIdx.x] = 0;
    __syncthreads();

    const int wid  = threadIdx.x >> 6;
    const int lane = threadIdx.x & 63;
    const int sub  = lane >> 4;            // which row of the quad
    const int grpb = lane & ~15;

    float lsum = 0.0f;
    for (int q = blockIdx.x * 4 + wid; q < NQUAD; q += gridDim.x * 4) {
        const float4 x = reinterpret_cast<const float4*>(logits)[q * 64 + lane];
        const int lab  = labels[SUPPORT + q * 4 + sub];
        float m = fmaxf(fmaxf(x.x, x.y), fmaxf(x.z, x.w));
        #pragma unroll
        for (int off = 1; off < 16; off <<= 1) m = fmaxf(m, __shfl_xor(m, off));
        float e = __expf(x.x - m) + __expf(x.y - m) + __expf(x.z - m) + __expf(x.w - m);
        #pragma unroll
        for (int off = 1; off < 16; off <<= 1) e += __shfl_xor(e, off);
        const int l3 = lab & 3;
        const float sel = l3 == 0 ? x.x : l3 == 1 ? x.y : l3 == 2 ? x.z : x.w;
        const float xl = __shfl(sel, grpb + (lab >> 2));
        if ((lane & 15) == 0) {
            lsum += m + __logf(e) - xl;
            atomicAdd(&ltc[lab], 1);
        }
    }
    #pragma unroll
    for (int off = 1; off < 64; off <<= 1) lsum += __shfl_xor(lsum, off);
    if (lane == 0) wsum[wid] = lsum;
    __syncthreads();
    if (threadIdx.x == 0)
        unsafeAtomicAdd(&ws->nll_sum[blockIdx.x & 7], wsum[0] + wsum[1] + wsum[2] + wsum[3]);
    if (threadIdx.x < NCLS) {
        int v = ltc[threadIdx.x];
        if (v) atomicAdd(&ws->tgt_cnt[threadIdx.x], v);
    }
}

// ---------------------------------------------------------------- finalize
__global__ void final_kernel(const Accum* __restrict__ ws, float* __restrict__ out) {
    if (threadIdx.x == 0 && blockIdx.x == 0) {
        long long pos = 0;
        for (int cc = 0; cc < NCLS; ++cc)
            pos += (long long)ws->sup_cnt[cc] * (long long)ws->tgt_cnt[cc];
        const long long tot = (long long)TARGET * SUPPORT;
        const double posn = (double)pos;
        const double negn = (double)(tot - pos);
        double cdf = 0.0, loss = 0.0;
        for (int t = 0; t <= 75; ++t) {        // slots 0..75 == bins 75..150
            double hp = (double)ws->hist_pos[0][t] + ws->hist_pos[1][t]
                      + ws->hist_pos[2][t] + ws->hist_pos[3][t];
            double ha = (double)ws->hist_all[0][t] + ws->hist_all[1][t]
                      + ws->hist_all[2][t] + ws->hist_all[3][t];
            cdf  += hp;
            loss += (ha - hp) * cdf;
        }
        out[0] = (float)(loss / (posn * negn));
        float nll = 0.0f;
        for (int i = 0; i < 8; ++i) nll += ws->nll_sum[i];
        out[1] = nll / (float)TARGET;
    }
}

// ---------------------------------------------------------------- launch
extern "C" void kernel_launch(void* const* d_in, const int* in_sizes, int n_in,
                              void* d_out, int out_size, void* d_ws, size_t ws_size,
                              hipStream_t stream) {
    const float* logits = (const float*)d_in[0];   // (65024, 64) f32
    const float* ip     = (const float*)d_in[1];   // (65024, 512) f32
    const int*   labels = (const int*)d_in[2];     // (65536,) int
    float* out = (float*)d_out;
    Accum* ws  = (Accum*)d_ws;

    hipMemsetAsync(ws, 0, sizeof(Accum), stream);
    prep_kernel<<<1, 512, 0, stream>>>(labels, ws);
    hist_kernel<<<2048, 256, 0, stream>>>(ip, labels, ws);
    direct_kernel<<<2048, 256, 0, stream>>>(logits, labels, ws);
    final_kernel<<<1, 64, 0, stream>>>(ws, out);
}

// Round 3
// 149.141 us; speedup vs baseline: 2.8847x; 2.6643x over previous
//
#include <hip/hip_runtime.h>

#define TSIZE   151
#define SUPPORT 512
#define TARGET  65024
#define NCLS    64
#define NPAIR   (TARGET / 2)  // 32512 row-pairs for gather_sum
#define NQUAD   (TARGET / 4)  // 16256 row-quads for direct kernel

struct Accum {
    float hist_pos_sp[8][80];   // spread pos-histogram accumulators (slots 0..75)
    float A[80];                // C[idx+1]  (cdf of pos hist)
    float B[80];                // Hpos[idx+1]
    float sum_all[8];
    float sum_pos[8];
    float nll_sum[8];
    int   sup_cnt[NCLS];
    int   tgt_cnt[NCLS];
    int   cls_off[NCLS + 1];
    int   cls_col[SUPPORT];
    unsigned long long mask[NCLS * 8];   // per-class 512-bit support membership
};

__device__ __forceinline__ void lds_fadd(float* p, float v) {
    __hip_atomic_fetch_add(p, v, __ATOMIC_RELAXED, __HIP_MEMORY_SCOPE_WORKGROUP);
}

// ---------------------------------------------------------------- prep
// One block, 512 threads: class masks, counts, CSR of support columns per class.
__global__ void prep_kernel(const int* __restrict__ labels, Accum* ws) {
    __shared__ int sh_cnt[NCLS], sh_off[NCLS], cur[NCLS];
    const int t = threadIdx.x;
    if (t < NCLS) { sh_cnt[t] = 0; cur[t] = 0; }
    __syncthreads();
    const int c = labels[t];
    atomicAdd(&sh_cnt[c], 1);
    atomicOr(&ws->mask[c * 8 + (t >> 6)], 1ull << (t & 63));
    __syncthreads();
    if (t == 0) {
        int o = 0;
        for (int i = 0; i < NCLS; ++i) { sh_off[i] = o; ws->cls_off[i] = o; o += sh_cnt[i]; }
        ws->cls_off[NCLS] = o;
    }
    __syncthreads();
    if (t < NCLS) ws->sup_cnt[t] = sh_cnt[t];
    const int slot = atomicAdd(&cur[c], 1);
    ws->cls_col[sh_off[c] + slot] = t;
}

// ---------------------------------------------------------------- pos histogram
// 2 threads per target row gather only the positive columns (~8/row avg).
__global__ __launch_bounds__(256) void pos_hist_kernel(const float* __restrict__ ip,
                                                       const int* __restrict__ labels,
                                                       Accum* __restrict__ ws) {
    __shared__ float hp[77][8];
    const int tid = threadIdx.x;
    for (int i = tid; i < 77 * 8; i += 256) (&hp[0][0])[i] = 0.0f;
    __syncthreads();

    const int t   = blockIdx.x * 256 + tid;
    const int row = t >> 1;
    const int par = t & 1;
    if (row < TARGET) {
        const int c    = labels[SUPPORT + row];
        const int base = ws->cls_off[c];
        const int end  = ws->cls_off[c + 1];
        const float* rptr = ip + (size_t)row * SUPPORT;
        const int cp = tid & 7;
        for (int i = base + par; i < end; i += 2) {
            const float s  = rptr[ws->cls_col[i]];
            const float u  = s * 75.0f;
            const float kf = floorf(u);
            const float fr = u - kf;
            int idx = (int)kf;
            idx = idx < 0 ? 0 : (idx > 74 ? 74 : idx);
            lds_fadd(&hp[idx][cp],     fr);
            lds_fadd(&hp[idx + 1][cp], 1.0f - fr);
        }
    }
    __syncthreads();
    if (tid < 76) {
        float s = 0.0f;
        #pragma unroll
        for (int r = 0; r < 8; ++r) s += hp[tid][r];
        if (s != 0.0f) unsafeAtomicAdd(&ws->hist_pos_sp[blockIdx.x & 7][tid], s);
    }
}

// ---------------------------------------------------------------- cdf build
__global__ void cdf_kernel(Accum* ws) {
    if (threadIdx.x == 0) {
        float H[77], C[77];
        for (int i = 0; i < 76; ++i) {
            float s = 0.0f;
            for (int r = 0; r < 8; ++r) s += ws->hist_pos_sp[r][i];
            H[i] = s;
        }
        H[76] = 0.0f;
        float c = 0.0f;
        for (int i = 0; i < 76; ++i) { c += H[i]; C[i] = c; }
        for (int idx = 0; idx < 75; ++idx) { ws->A[idx] = C[idx + 1]; ws->B[idx] = H[idx + 1]; }
        ws->A[75] = C[75]; ws->B[75] = 0.0f;
    }
}

// ---------------------------------------------------------------- main pass
// Stream all 33.3M elements once; per element: 2 LDS reads + FMA into register
// sums. No per-element atomics.
__global__ __launch_bounds__(256) void gather_sum_kernel(const float* __restrict__ ip,
                                                         const int* __restrict__ labels,
                                                         Accum* __restrict__ ws) {
    __shared__ float sA[80], sB[80];
    __shared__ float red[8];
    const int tid = threadIdx.x;
    if (tid < 76) { sA[tid] = ws->A[tid]; sB[tid] = ws->B[tid]; }
    __syncthreads();

    const int half = tid >> 7;            // which row of the pair
    const int word = (tid & 127) >> 4;    // u64 word of the 512-bit mask
    const int bit0 = (tid << 2) & 63;     // bit of first of the 4 columns

    float s_all = 0.0f, s_pos = 0.0f;
    int rp = blockIdx.x;
    float4 v; unsigned long long mw = 0;
    if (rp < NPAIR) {
        v = reinterpret_cast<const float4*>(ip)[rp * 256 + tid];
        const int lab = labels[SUPPORT + rp * 2 + half];
        mw = ws->mask[lab * 8 + word];
    }
    while (rp < NPAIR) {
        const int rpn = rp + gridDim.x;
        float4 vn; unsigned long long mwn = 0;
        if (rpn < NPAIR) {
            vn = reinterpret_cast<const float4*>(ip)[rpn * 256 + tid];
            const int labn = labels[SUPPORT + rpn * 2 + half];
            mwn = ws->mask[labn * 8 + word];
        }
        const unsigned nib = (unsigned)(mw >> bit0) & 0xFu;
        #pragma unroll
        for (int e = 0; e < 4; ++e) {
            const float s  = e == 0 ? v.x : e == 1 ? v.y : e == 2 ? v.z : v.w;
            const float u  = s * 75.0f;
            const float kf = floorf(u);
            const float fr = u - kf;
            int idx = (int)kf;
            idx = idx < 0 ? 0 : (idx > 74 ? 74 : idx);
            const float g = sA[idx] - fr * sB[idx];
            s_all += g;
            if (nib & (1u << e)) s_pos += g;
        }
        v = vn; mw = mwn; rp = rpn;
    }

    #pragma unroll
    for (int off = 1; off < 64; off <<= 1) {
        s_all += __shfl_xor(s_all, off);
        s_pos += __shfl_xor(s_pos, off);
    }
    if ((tid & 63) == 0) { red[tid >> 6] = s_all; red[4 + (tid >> 6)] = s_pos; }
    __syncthreads();
    if (tid == 0) unsafeAtomicAdd(&ws->sum_all[blockIdx.x & 7], red[0] + red[1] + red[2] + red[3]);
    if (tid == 1) unsafeAtomicAdd(&ws->sum_pos[blockIdx.x & 7], red[4] + red[5] + red[6] + red[7]);
}

// ---------------------------------------------------------------- direct loss
// 4 rows per wave: 16-lane group per row, float4 per lane.
__global__ __launch_bounds__(256) void direct_kernel(const float* __restrict__ logits,
                                                     const int* __restrict__ labels,
                                                     Accum* __restrict__ ws) {
    __shared__ int   ltc[NCLS];
    __shared__ float wsum[4];
    if (threadIdx.x < NCLS) ltc[threadIdx.x] = 0;
    __syncthreads();

    const int wid  = threadIdx.x >> 6;
    const int lane = threadIdx.x & 63;
    const int sub  = lane >> 4;
    const int grpb = lane & ~15;

    float lsum = 0.0f;
    for (int q = blockIdx.x * 4 + wid; q < NQUAD; q += gridDim.x * 4) {
        const float4 x = reinterpret_cast<const float4*>(logits)[q * 64 + lane];
        const int lab  = labels[SUPPORT + q * 4 + sub];
        float m = fmaxf(fmaxf(x.x, x.y), fmaxf(x.z, x.w));
        #pragma unroll
        for (int off = 1; off < 16; off <<= 1) m = fmaxf(m, __shfl_xor(m, off));
        float e = __expf(x.x - m) + __expf(x.y - m) + __expf(x.z - m) + __expf(x.w - m);
        #pragma unroll
        for (int off = 1; off < 16; off <<= 1) e += __shfl_xor(e, off);
        const int l3 = lab & 3;
        const float sel = l3 == 0 ? x.x : l3 == 1 ? x.y : l3 == 2 ? x.z : x.w;
        const float xl = __shfl(sel, grpb + (lab >> 2));
        if ((lane & 15) == 0) {
            lsum += m + __logf(e) - xl;
            atomicAdd(&ltc[lab], 1);
        }
    }
    #pragma unroll
    for (int off = 1; off < 64; off <<= 1) lsum += __shfl_xor(lsum, off);
    if (lane == 0) wsum[wid] = lsum;
    __syncthreads();
    if (threadIdx.x == 0)
        unsafeAtomicAdd(&ws->nll_sum[blockIdx.x & 7], wsum[0] + wsum[1] + wsum[2] + wsum[3]);
    if (threadIdx.x < NCLS) {
        int v = ltc[threadIdx.x];
        if (v) atomicAdd(&ws->tgt_cnt[threadIdx.x], v);
    }
}

// ---------------------------------------------------------------- finalize
__global__ void final_kernel(const Accum* __restrict__ ws, float* __restrict__ out) {
    if (threadIdx.x == 0 && blockIdx.x == 0) {
        long long pos = 0;
        for (int c = 0; c < NCLS; ++c)
            pos += (long long)ws->sup_cnt[c] * (long long)ws->tgt_cnt[c];
        const long long tot = (long long)TARGET * SUPPORT;
        double S = 0.0, P = 0.0;
        for (int i = 0; i < 8; ++i) { S += ws->sum_all[i]; P += ws->sum_pos[i]; }
        out[0] = (float)((S - P) / ((double)pos * (double)(tot - pos)));
        float nll = 0.0f;
        for (int i = 0; i < 8; ++i) nll += ws->nll_sum[i];
        out[1] = nll / (float)TARGET;
    }
}

// ---------------------------------------------------------------- launch
extern "C" void kernel_launch(void* const* d_in, const int* in_sizes, int n_in,
                              void* d_out, int out_size, void* d_ws, size_t ws_size,
                              hipStream_t stream) {
    const float* logits = (const float*)d_in[0];   // (65024, 64) f32
    const float* ip     = (const float*)d_in[1];   // (65024, 512) f32
    const int*   labels = (const int*)d_in[2];     // (65536,) int
    float* out = (float*)d_out;
    Accum* ws  = (Accum*)d_ws;

    hipMemsetAsync(ws, 0, sizeof(Accum), stream);
    prep_kernel<<<1, 512, 0, stream>>>(labels, ws);
    pos_hist_kernel<<<(TARGET * 2 + 255) / 256, 256, 0, stream>>>(ip, labels, ws);
    cdf_kernel<<<1, 64, 0, stream>>>(ws);
    direct_kernel<<<2048, 256, 0, stream>>>(logits, labels, ws);
    gather_sum_kernel<<<2048, 256, 0, stream>>>(ip, labels, ws);
    final_kernel<<<1, 64, 0, stream>>>(ws, out);
}